// Round 16
// baseline (296.158 us; speedup 1.0000x reference)
//
#include <hip/hip_runtime.h>
#include <math.h>

// Problem dims (fixed by reference)
#define CC 4
#define FE 32
#define HH 64
#define EBS 256
#define KEXT 544          // 512 + 32 (8 xbar cols + 24 zero pad), 17 K-steps of 32
#define ASTR 69           // uint4 per A-tile LDS row

typedef __attribute__((ext_vector_type(8))) short bf16x8;
typedef __attribute__((ext_vector_type(4))) float f32x4;

// bf16 round-to-nearest-even pack
__device__ inline unsigned short f2bf(float f) {
    unsigned u = __float_as_uint(f);
    u += 0x7fffu + ((u >> 16) & 1u);
    return (unsigned short)(u >> 16);
}
__device__ inline float bf2f(unsigned short b) {
    return __uint_as_float(((unsigned)b) << 16);
}

// ---------------------------------------------------------------------------
// Node prep (one wave per node, shuffle-based, low-VGPR)
// ---------------------------------------------------------------------------
__global__ __launch_bounds__(256) void k_nodeprep(
    const float* __restrict__ node_input, const float* __restrict__ node_attr,
    const float* __restrict__ W_lin1, const float* __restrict__ W_sc,
    const float* __restrict__ W_lin2,
    float* __restrict__ xbuf, float* __restrict__ sbuf,
    float* __restrict__ w2n_ws, int N)
{
    const float c_s = 0.3826834323650898f;
    const float c_x_scaled = 0.9238795325112867f * 0.35355339059327373f; // c_x/sqrt(8)
    int node = blockIdx.x * 4 + (threadIdx.x >> 6);
    int lane = threadIdx.x & 63;
    if (node >= N) return;

    float attr_own = (lane < 16) ? node_attr[(size_t)node * 16 + lane] : 0.f;
    float ni_own   = (lane < 32) ? node_input[(size_t)node * 32 + lane] : 0.f;

    int iw = lane >> 3, jw = lane & 7;
    float wb1 = 0.f, wbs = 0.f, w2n = 0.f;
    #pragma unroll
    for (int a = 0; a < 16; ++a) {
        float fa = __shfl(attr_own, a);
        int idx = (iw * 16 + a) * 8 + jw;
        wb1 += fa * W_lin1[idx];
        wbs += fa * W_sc[idx];
        w2n += fa * W_lin2[idx];
    }
    w2n_ws[(size_t)node * 64 + lane] = c_x_scaled * w2n;

    int c_ = (lane >> 3) & 3, jo = lane & 7;
    float xo = 0.f, so = 0.f;
    #pragma unroll
    for (int i = 0; i < 8; ++i) {
        float niv = __shfl(ni_own, c_ * 8 + i);
        xo += niv * __shfl(wb1, i * 8 + jo);
        so += niv * __shfl(wbs, i * 8 + jo);
    }
    if (lane < 32) {
        xbuf[(size_t)node * 32 + lane] = xo;
        sbuf[(size_t)node * 32 + lane] = c_s * so;
    }
}

// ---------------------------------------------------------------------------
// CSR build over edge_dst
// ---------------------------------------------------------------------------
__global__ __launch_bounds__(256) void k_hist(
    const int* __restrict__ edge_dst, int* __restrict__ counts, int E)
{
    int e = blockIdx.x * 256 + threadIdx.x;
    if (e < E) atomicAdd(&counts[edge_dst[e]], 1);
}

// Parallel scan stage A: per-1024-tile exclusive scan + tile totals
__global__ __launch_bounds__(1024) void k_scanA(
    const int* __restrict__ counts, int* __restrict__ offsets,
    int* __restrict__ btot, int N)
{
    __shared__ int wsum[16];
    __shared__ int wpre[16];
    int tid = threadIdx.x, wid = tid >> 6, lane = tid & 63;
    int idx = blockIdx.x * 1024 + tid;
    int v = (idx < N) ? counts[idx] : 0;
    int x = v;
    #pragma unroll
    for (int s = 1; s < 64; s <<= 1) {
        int y = __shfl_up(x, s);
        if (lane >= s) x += y;
    }
    if (lane == 63) wsum[wid] = x;
    __syncthreads();
    if (wid == 0) {
        int wv = (lane < 16) ? wsum[lane] : 0;
        int wx = wv;
        #pragma unroll
        for (int s = 1; s < 16; s <<= 1) {
            int y = __shfl_up(wx, s);
            if (lane >= s) wx += y;
        }
        if (lane < 16) wpre[lane] = wx - wv;
    }
    __syncthreads();
    int excl = wpre[wid] + (x - v);
    if (idx < N) offsets[idx] = excl;
    if (tid == 1023) btot[blockIdx.x] = excl + v;
}

// stage B: single-block exclusive scan of tile totals (nb <= 1024)
__global__ __launch_bounds__(1024) void k_scanB(int* __restrict__ btot, int nb)
{
    __shared__ int wsum[16];
    __shared__ int wpre[16];
    int tid = threadIdx.x, wid = tid >> 6, lane = tid & 63;
    int v = (tid < nb) ? btot[tid] : 0;
    int x = v;
    #pragma unroll
    for (int s = 1; s < 64; s <<= 1) {
        int y = __shfl_up(x, s);
        if (lane >= s) x += y;
    }
    if (lane == 63) wsum[wid] = x;
    __syncthreads();
    if (wid == 0) {
        int wv = (lane < 16) ? wsum[lane] : 0;
        int wx = wv;
        #pragma unroll
        for (int s = 1; s < 16; s <<= 1) {
            int y = __shfl_up(wx, s);
            if (lane >= s) wx += y;
        }
        if (lane < 16) wpre[lane] = wx - wv;
    }
    __syncthreads();
    if (tid < nb) btot[tid] = wpre[wid] + (x - v);
}

// stage C: add tile offsets, write cursor
__global__ __launch_bounds__(256) void k_scanC(
    int* __restrict__ offsets, const int* __restrict__ btot,
    int* __restrict__ cursor, int N)
{
    int i = blockIdx.x * 256 + threadIdx.x;
    if (i < N) {
        int o = offsets[i] + btot[i >> 10];
        offsets[i] = o;
        cursor[i] = o;
    }
}

// fill permutation: srcs[pos] = src; epos[e] = pos (for perm-ordered H write)
__global__ __launch_bounds__(256) void k_fill(
    const int* __restrict__ edge_dst, const int* __restrict__ edge_src,
    int* __restrict__ cursor, int* __restrict__ srcs, int* __restrict__ epos, int E)
{
    int e = blockIdx.x * 256 + threadIdx.x;
    if (e < E) {
        int pos = atomicAdd(&cursor[edge_dst[e]], 1);
        srcs[pos] = edge_src[e];
        epos[e] = pos;
    }
}

// ---------------------------------------------------------------------------
// Degree sort (LDS-privatized — round-11 lesson: NO contended global atomics).
// dhistA: per-block LDS histogram -> bh[bin][block] (bin-major).
// ---------------------------------------------------------------------------
__global__ __launch_bounds__(1024) void k_dhistA(
    const int* __restrict__ counts, int* __restrict__ bh, int N, int NB)
{
    __shared__ int h[64];
    if (threadIdx.x < 64) h[threadIdx.x] = 0;
    __syncthreads();
    int i = blockIdx.x * 1024 + threadIdx.x;
    if (i < N) {
        int b = counts[i]; if (b > 63) b = 63;
        atomicAdd(&h[b], 1);
    }
    __syncthreads();
    if (threadIdx.x < 64) bh[threadIdx.x * NB + blockIdx.x] = h[threadIdx.x];
}

// dhistB: in-place exclusive scan of bh (flat bin-major order == position base
// for each (bin,block) range). Proven k_scan skeleton.
__global__ __launch_bounds__(1024) void k_dhistB(int* __restrict__ bh, int L)
{
    __shared__ int wsum[16];
    __shared__ int wpre[16];
    __shared__ int s_tot;
    __shared__ int s_carry;
    int tid = threadIdx.x, wid = tid >> 6, lane = tid & 63;
    if (tid == 0) s_carry = 0;
    __syncthreads();
    for (int base = 0; base < L; base += 1024) {
        int idx = base + tid;
        int v = (idx < L) ? bh[idx] : 0;
        int x = v;
        #pragma unroll
        for (int s = 1; s < 64; s <<= 1) {
            int y = __shfl_up(x, s);
            if (lane >= s) x += y;
        }
        if (lane == 63) wsum[wid] = x;
        __syncthreads();
        if (wid == 0) {
            int wv = (lane < 16) ? wsum[lane] : 0;
            int wx = wv;
            #pragma unroll
            for (int s = 1; s < 16; s <<= 1) {
                int y = __shfl_up(wx, s);
                if (lane >= s) wx += y;
            }
            if (lane < 16) wpre[lane] = wx - wv;
            if (lane == 15) s_tot = wx;
        }
        __syncthreads();
        if (idx < L) bh[idx] = s_carry + wpre[wid] + (x - v);
        __syncthreads();
        if (tid == 0) s_carry += s_tot;
        __syncthreads();
    }
}

// dscatter2: recompute LDS ranks, place node at bh-base + rank.
__global__ __launch_bounds__(1024) void k_dscatter2(
    const int* __restrict__ counts, const int* __restrict__ bh,
    int* __restrict__ nodeperm, int N, int NB)
{
    __shared__ int cur[64];
    if (threadIdx.x < 64) cur[threadIdx.x] = 0;
    __syncthreads();
    int i = blockIdx.x * 1024 + threadIdx.x;
    if (i < N) {
        int b = counts[i]; if (b > 63) b = 63;
        int rank = atomicAdd(&cur[b], 1);
        nodeperm[bh[b * NB + blockIdx.x] + rank] = i;
    }
}

// ---------------------------------------------------------------------------
// x gather: xg[pos, :] = xbuf[srcs[pos], :]  (f32, perm order).
// ---------------------------------------------------------------------------
__global__ __launch_bounds__(256) void k_xgather(
    const int* __restrict__ srcs, const float* __restrict__ xin,
    float* __restrict__ xg, int E)
{
    int t = blockIdx.x * 256 + threadIdx.x;
    if (t >= E * 4) return;
    int pos = t >> 2, q = t & 3;
    int src = srcs[pos];
    const float4* xp = reinterpret_cast<const float4*>(xin + (size_t)src * 32 + q * 8);
    float4 a = xp[0], b = xp[1];
    float4* op = reinterpret_cast<float4*>(xg + (size_t)pos * 32 + q * 8);
    op[0] = a; op[1] = b;
}

// ---------------------------------------------------------------------------
// Pack W2 (+ b2 as K-rows 512..519, zeros 520..543) into MFMA B-frag order.
// ---------------------------------------------------------------------------
__global__ __launch_bounds__(256) void k_prep_bfrag(
    const float* __restrict__ fc_w2, const float* __restrict__ fc_b2,
    unsigned short* __restrict__ Bfrag)
{
    int t = blockIdx.x * 256 + threadIdx.x;
    if (t >= KEXT * 64) return;
    int kappa = t >> 6, nu = t & 63;
    int d = nu >> 3, o = nu & 7;
    float val;
    if (kappa < 512)      val = fc_w2[(size_t)(kappa >> 3) * 512 + d * 64 + (kappa & 7) * 8 + o];
    else if (kappa < 520) val = fc_b2[d * 64 + (kappa & 7) * 8 + o];
    else                  val = 0.f;
    int kk = kappa >> 5;
    int lane = ((kappa >> 3) & 3) * 16 + (nu & 15);
    int ct = nu >> 4;
    int j = kappa & 7;
    Bfrag[(size_t)((kk * 4 + ct) * 64 + lane) * 8 + j] = f2bf(val);
}

// ---------------------------------------------------------------------------
// Pack W1 [32,64] into MFMA B-frag order (one K-step).
// ---------------------------------------------------------------------------
__global__ __launch_bounds__(256) void k_prep_bfrag1(
    const float* __restrict__ fc_w1, unsigned short* __restrict__ Bfrag1)
{
    int t = blockIdx.x * 256 + threadIdx.x;
    if (t >= 4 * 64 * 8) return;
    int j = t & 7, l = (t >> 3) & 63, ct = t >> 9;
    int k = (l >> 4) * 8 + j;
    int n = ct * 16 + (l & 15);
    Bfrag1[t] = f2bf(fc_w1[(size_t)k * HH + n]);
}

// ---------------------------------------------------------------------------
// H build via MFMA — writes H in PERM ORDER (scatter via epos).
// ---------------------------------------------------------------------------
__global__ __launch_bounds__(256) void k_hsilu(
    const float* __restrict__ edge_features,
    const unsigned short* __restrict__ Bfrag1, const float* __restrict__ fc_b1,
    const int* __restrict__ epos,
    unsigned short* __restrict__ H, int E)
{
    int wid = threadIdx.x >> 6, lane = threadIdx.x & 63;
    int e0 = (blockIdx.x * 4 + wid) * 16;
    if (e0 >= E) return;

    bf16x8 b[4];
    #pragma unroll
    for (int ct = 0; ct < 4; ++ct) {
        uint4 bv = reinterpret_cast<const uint4*>(Bfrag1)[ct * 64 + lane];
        b[ct] = *reinterpret_cast<bf16x8*>(&bv);
    }
    float bias[4];
    #pragma unroll
    for (int ct = 0; ct < 4; ++ct) bias[ct] = fc_b1[ct * 16 + (lane & 15)];

    int pr[4];
    #pragma unroll
    for (int v = 0; v < 4; ++v) {
        int r = e0 + (lane >> 4) * 4 + v;
        pr[v] = (r < E) ? epos[r] : -1;
    }

    int row = e0 + (lane & 15);
    if (row >= E) row = E - 1;
    const float4* ap = reinterpret_cast<const float4*>(
        edge_features + (size_t)row * FE + (lane >> 4) * 8);
    float4 a0 = ap[0], a1 = ap[1];
    unsigned au[4];
    au[0] = (unsigned)f2bf(a0.x) | ((unsigned)f2bf(a0.y) << 16);
    au[1] = (unsigned)f2bf(a0.z) | ((unsigned)f2bf(a0.w) << 16);
    au[2] = (unsigned)f2bf(a1.x) | ((unsigned)f2bf(a1.y) << 16);
    au[3] = (unsigned)f2bf(a1.z) | ((unsigned)f2bf(a1.w) << 16);
    bf16x8 a = *reinterpret_cast<bf16x8*>(au);

    f32x4 acc[4];
    #pragma unroll
    for (int ct = 0; ct < 4; ++ct) {
        acc[ct] = (f32x4){0.f, 0.f, 0.f, 0.f};
        acc[ct] = __builtin_amdgcn_mfma_f32_16x16x32_bf16(a, b[ct], acc[ct], 0, 0, 0);
    }

    #pragma unroll
    for (int ct = 0; ct < 4; ++ct) {
        #pragma unroll
        for (int v = 0; v < 4; ++v) {
            if (pr[v] >= 0) {
                float x = acc[ct][v] + bias[ct];
                float s = x / (1.f + __expf(-x));
                H[(size_t)pr[v] * HH + ct * 16 + (lane & 15)] = f2bf(s);
            }
        }
    }
}

// ---------------------------------------------------------------------------
// FUSED zbuild + GEMM (R15 structure + degree-matched node assignment).
// Block = 4 waves = 4 nodes of EQUAL degree (via nodeperm) = one MFMA tile.
// Phase 1: pure streaming edge accumulation (H and xg both in perm order).
// Phase 2: pack A-tile into LDS. Phase 3: 17 MFMA. Store via nodeperm.
// ---------------------------------------------------------------------------
__global__ __launch_bounds__(256) void k_zgemm(
    const unsigned short* __restrict__ H, const float* __restrict__ xg,
    const int* __restrict__ offsets, const int* __restrict__ counts,
    const int* __restrict__ nodeperm,
    const unsigned short* __restrict__ Bfrag,
    float* __restrict__ out, int N)
{
    __shared__ uint4 alds[16 * ASTR];   // 17664 B
    int wid = threadIdx.x >> 6, lane = threadIdx.x & 63;
    int nidx = blockIdx.x * 4 + wid;
    bool valid = (nidx < N);
    int node = valid ? nodeperm[nidx] : 0;

    // ---- Phase 1: streaming edge accumulation (lane k owns h[e,k]) ----
    float z[CC][8];
    #pragma unroll
    for (int c = 0; c < CC; ++c)
        #pragma unroll
        for (int i = 0; i < 8; ++i) z[c][i] = 0.f;
    float xsown = 0.f;

    int off = 0, cnt = 0;
    if (valid) { off = offsets[node]; cnt = counts[node]; }
    #pragma unroll 2
    for (int j = 0; j < cnt; ++j) {
        size_t pos = (size_t)(off + j);
        float hk = bf2f(H[pos * HH + lane]);                       // seq 128B rows
        const float4* xp = reinterpret_cast<const float4*>(xg + pos * 32);  // seq rows
        float xs[32];
        #pragma unroll
        for (int q = 0; q < 8; ++q) {
            float4 v = xp[q];
            xs[q * 4 + 0] = v.x; xs[q * 4 + 1] = v.y;
            xs[q * 4 + 2] = v.z; xs[q * 4 + 3] = v.w;
        }
        #pragma unroll
        for (int c = 0; c < CC; ++c)
            #pragma unroll
            for (int i = 0; i < 8; ++i)
                z[c][i] += hk * xs[c * 8 + i];
        xsown += xg[pos * 32 + (lane & 31)];
    }

    // ---- Phase 2: pack this node's 4 rows into the LDS A-tile ----
    #pragma unroll
    for (int c = 0; c < CC; ++c) {
        uint4 pk;
        pk.x = (unsigned)f2bf(z[c][0]) | ((unsigned)f2bf(z[c][1]) << 16);
        pk.y = (unsigned)f2bf(z[c][2]) | ((unsigned)f2bf(z[c][3]) << 16);
        pk.z = (unsigned)f2bf(z[c][4]) | ((unsigned)f2bf(z[c][5]) << 16);
        pk.w = (unsigned)f2bf(z[c][6]) | ((unsigned)f2bf(z[c][7]) << 16);
        alds[(wid * 4 + c) * ASTR + lane] = pk;
    }
    float xb[8];
    #pragma unroll
    for (int i = 0; i < 8; ++i) xb[i] = __shfl(xsown, (lane & 3) * 8 + i);
    int r4 = wid * 4;
    if (lane < 4) {
        uint4 pk;
        pk.x = (unsigned)f2bf(xb[0]) | ((unsigned)f2bf(xb[1]) << 16);
        pk.y = (unsigned)f2bf(xb[2]) | ((unsigned)f2bf(xb[3]) << 16);
        pk.z = (unsigned)f2bf(xb[4]) | ((unsigned)f2bf(xb[5]) << 16);
        pk.w = (unsigned)f2bf(xb[6]) | ((unsigned)f2bf(xb[7]) << 16);
        alds[(r4 + lane) * ASTR + 64] = pk;
    } else if (lane < 16) {
        int j = lane - 4;
        uint4 zz; zz.x = 0u; zz.y = 0u; zz.z = 0u; zz.w = 0u;
        alds[(r4 + (j & 3)) * ASTR + 65 + (j >> 2)] = zz;
    }

    // ---- B fragments for ct = wid ----
    bf16x8 bfr[17];
    #pragma unroll
    for (int kk = 0; kk < 16; ++kk) {
        uint4 bv = reinterpret_cast<const uint4*>(Bfrag)[(kk * 4 + wid) * 64 + lane];
        bfr[kk] = *reinterpret_cast<bf16x8*>(&bv);
    }
    {
        uint4 bv = reinterpret_cast<const uint4*>(Bfrag)[(64 + wid) * 64 + lane];
        bfr[16] = *reinterpret_cast<bf16x8*>(&bv);
    }

    __syncthreads();

    // ---- Phase 3: GEMM, wave = ct ----
    f32x4 acc = (f32x4){0.f, 0.f, 0.f, 0.f};
    #pragma unroll
    for (int kk = 0; kk < 16; ++kk) {
        uint4 av = alds[(lane & 15) * ASTR + kk * 4 + (lane >> 4)];
        bf16x8 a = *reinterpret_cast<bf16x8*>(&av);
        acc = __builtin_amdgcn_mfma_f32_16x16x32_bf16(a, bfr[kk], acc, 0, 0, 0);
    }
    {
        uint4 av = alds[(lane & 15) * ASTR + 64 + (lane >> 4)];
        bf16x8 a = *reinterpret_cast<bf16x8*>(&av);
        acc = __builtin_amdgcn_mfma_f32_16x16x32_bf16(a, bfr[16], acc, 0, 0, 0);
    }

    // store: 16-lane group q = local node slot; remap through nodeperm
    int qslot = lane >> 4;
    int nidx_q = blockIdx.x * 4 + qslot;
    if (nidx_q < N) {
        int rn = nodeperm[nidx_q];
        #pragma unroll
        for (int v = 0; v < 4; ++v)
            out[(size_t)(rn * 4 + v) * 64 + wid * 16 + (lane & 15)] = acc[v];
    }
}

// ---------------------------------------------------------------------------
// Kernel C: shuffle lin2 + self-connection epilogue (in place on out).
// ---------------------------------------------------------------------------
__global__ __launch_bounds__(256) void k_node_out(
    const float* __restrict__ sbuf, const float* __restrict__ w2n_ws,
    float* __restrict__ out, int N)
{
    int node = blockIdx.x * 4 + (threadIdx.x >> 6);
    int lane = threadIdx.x & 63;
    if (node >= N) return;
    int d = lane >> 3, p = lane & 7;

    float w2 = w2n_ws[(size_t)node * 64 + lane];
    float s_own = sbuf[(size_t)node * 32 + (lane & 31)];

    float w2sh[8];
    #pragma unroll
    for (int o = 0; o < 8; ++o) w2sh[o] = __shfl(w2, o * 8 + p);

    float* rowp = out + (size_t)node * 256;
    #pragma unroll
    for (int c = 0; c < CC; ++c) {
        float a_own = rowp[c * 64 + lane];
        float res = 0.f;
        #pragma unroll
        for (int o = 0; o < 8; ++o)
            res += __shfl(a_own, d * 8 + o) * w2sh[o];
        float sval = __shfl(s_own, c * 8 + p);
        rowp[c * 64 + lane] = sval + res;
    }
}

// ---------------------------------------------------------------------------
// Fallback edge kernel (global atomics) — only if ws too small.
// ---------------------------------------------------------------------------
__global__ __launch_bounds__(EBS) void k_edge_atomic(
    const float* __restrict__ edge_features,
    const float* __restrict__ fc_w1, const float* __restrict__ fc_b1,
    const float* __restrict__ fc_w2, const float* __restrict__ fc_b2,
    const int* __restrict__ edge_src, const int* __restrict__ edge_dst,
    const float* __restrict__ xin, float* __restrict__ agg, int E)
{
    __shared__ float hlds[HH * EBS];
    int e = blockIdx.x * EBS + threadIdx.x;
    if (e >= E) return;
    float h[HH];
    #pragma unroll
    for (int k = 0; k < HH; ++k) h[k] = fc_b1[k];
    const float4* efp = reinterpret_cast<const float4*>(edge_features + (size_t)e * FE);
    #pragma unroll
    for (int fq = 0; fq < FE / 4; ++fq) {
        float4 efv = efp[fq];
        float ev[4] = {efv.x, efv.y, efv.z, efv.w};
        #pragma unroll
        for (int fs = 0; fs < 4; ++fs) {
            float evv = ev[fs];
            const float4* w1p = reinterpret_cast<const float4*>(fc_w1 + (fq * 4 + fs) * HH);
            #pragma unroll
            for (int q = 0; q < HH / 4; ++q) {
                float4 w = w1p[q];
                h[q * 4 + 0] += evv * w.x;
                h[q * 4 + 1] += evv * w.y;
                h[q * 4 + 2] += evv * w.z;
                h[q * 4 + 3] += evv * w.w;
            }
        }
    }
    #pragma unroll
    for (int k = 0; k < HH; ++k) {
        float v = h[k];
        hlds[k * EBS + threadIdx.x] = v / (1.f + __expf(-v));
    }
    int src = edge_src[e], dst = edge_dst[e];
    float xs[32];
    const float4* xp = reinterpret_cast<const float4*>(xin + (size_t)src * 32);
    #pragma unroll
    for (int q = 0; q < 8; ++q) {
        float4 v = xp[q];
        xs[q * 4 + 0] = v.x; xs[q * 4 + 1] = v.y;
        xs[q * 4 + 2] = v.z; xs[q * 4 + 3] = v.w;
    }
    float* outp = agg + (size_t)dst * 256;
    #pragma unroll 1
    for (int d = 0; d < 8; ++d) {
        float t[64];
        const float4* b2p = reinterpret_cast<const float4*>(fc_b2 + d * 64);
        #pragma unroll
        for (int q = 0; q < 16; ++q) {
            float4 v = b2p[q];
            t[q * 4 + 0] = v.x; t[q * 4 + 1] = v.y;
            t[q * 4 + 2] = v.z; t[q * 4 + 3] = v.w;
        }
        for (int k = 0; k < HH; ++k) {
            float hv = hlds[k * EBS + threadIdx.x];
            const float4* wp = reinterpret_cast<const float4*>(fc_w2 + (size_t)k * 512 + d * 64);
            #pragma unroll
            for (int q = 0; q < 16; ++q) {
                float4 w = wp[q];
                t[q * 4 + 0] += hv * w.x;
                t[q * 4 + 1] += hv * w.y;
                t[q * 4 + 2] += hv * w.z;
                t[q * 4 + 3] += hv * w.w;
            }
        }
        #pragma unroll
        for (int c = 0; c < CC; ++c) {
            #pragma unroll
            for (int o = 0; o < 8; ++o) {
                float acc = 0.f;
                #pragma unroll
                for (int i = 0; i < 8; ++i) acc += xs[c * 8 + i] * t[i * 8 + o];
                atomicAdd(outp + c * 64 + d * 8 + o, acc);
            }
        }
    }
}

// ---------------------------------------------------------------------------
extern "C" void kernel_launch(void* const* d_in, const int* in_sizes, int n_in,
                              void* d_out, int out_size, void* d_ws, size_t ws_size,
                              hipStream_t stream)
{
    const float* node_input    = (const float*)d_in[0];
    const float* node_attr     = (const float*)d_in[1];
    const float* edge_features = (const float*)d_in[2];
    const float* W_sc          = (const float*)d_in[3];
    const float* W_lin1        = (const float*)d_in[4];
    const float* W_lin2        = (const float*)d_in[5];
    const float* fc_w1         = (const float*)d_in[6];
    const float* fc_b1         = (const float*)d_in[7];
    const float* fc_w2         = (const float*)d_in[8];
    const float* fc_b2         = (const float*)d_in[9];
    const int*   edge_src      = (const int*)d_in[10];
    const int*   edge_dst      = (const int*)d_in[11];

    const int N = in_sizes[1] / 16;
    const int E = in_sizes[10];
    const int nb = (N + 1023) / 1024;   // also NB for degree sort

    char* ws = (char*)d_ws;
    size_t off = 0;
    auto take = [&](size_t bytes) { char* p = ws + off; off += (bytes + 15) & ~(size_t)15; return p; };
    float* xbuf            = (float*)take((size_t)N * 32 * sizeof(float));
    float* sbuf            = (float*)take((size_t)N * 32 * sizeof(float));
    float* w2n_ws          = (float*)take((size_t)N * 64 * sizeof(float));
    int*   counts          = (int*)take((size_t)N * sizeof(int));
    int*   offsets         = (int*)take((size_t)N * sizeof(int));
    int*   cursor          = (int*)take((size_t)N * sizeof(int));
    int*   btot            = (int*)take((size_t)1024 * sizeof(int));
    int*   bh              = (int*)take((size_t)64 * nb * sizeof(int));
    int*   nodeperm        = (int*)take((size_t)N * sizeof(int));
    int*   srcs            = (int*)take((size_t)E * sizeof(int));
    int*   epos            = (int*)take((size_t)E * sizeof(int));
    unsigned short* Bfrag  = (unsigned short*)take((size_t)17 * 4 * 64 * 8 * sizeof(unsigned short));
    unsigned short* Bfrag1 = (unsigned short*)take((size_t)4 * 64 * 8 * sizeof(unsigned short));
    unsigned short* Hbuf   = (unsigned short*)take((size_t)E * HH * sizeof(unsigned short));
    float* xg              = (float*)take((size_t)E * 32 * sizeof(float));
    bool fast = (off <= ws_size);

    float* out = (float*)d_out;

    // node prep: x, c_s*s, w2n (one wave per node, shuffle-based)
    k_nodeprep<<<(N + 3) / 4, 256, 0, stream>>>(
        node_input, node_attr, W_lin1, W_sc, W_lin2, xbuf, sbuf, w2n_ws, N);

    if (fast) {
        // CSR over edge_dst, parallel scan, srcs + epos
        hipMemsetAsync(counts, 0, (size_t)N * sizeof(int), stream);
        k_hist<<<(E + 255) / 256, 256, 0, stream>>>(edge_dst, counts, E);
        k_scanA<<<nb, 1024, 0, stream>>>(counts, offsets, btot, N);
        k_scanB<<<1, 1024, 0, stream>>>(btot, nb);
        k_scanC<<<(N + 255) / 256, 256, 0, stream>>>(offsets, btot, cursor, N);
        k_fill<<<(E + 255) / 256, 256, 0, stream>>>(edge_dst, edge_src, cursor, srcs, epos, E);
        // degree-balanced node permutation (LDS-privatized counting sort)
        k_dhistA<<<nb, 1024, 0, stream>>>(counts, bh, N, nb);
        k_dhistB<<<1, 1024, 0, stream>>>(bh, 64 * nb);
        k_dscatter2<<<nb, 1024, 0, stream>>>(counts, bh, nodeperm, N, nb);
        // weight packs
        k_prep_bfrag1<<<(4 * 64 * 8 + 255) / 256, 256, 0, stream>>>(fc_w1, Bfrag1);
        k_prep_bfrag<<<(KEXT * 64 + 255) / 256, 256, 0, stream>>>(fc_w2, fc_b2, Bfrag);
        // radial layer-1 via MFMA, H written in PERM order (scatter)
        k_hsilu<<<(E + 63) / 64, 256, 0, stream>>>(edge_features, Bfrag1, fc_b1, epos, Hbuf, E);
        // x gather into perm order (random reads hidden by TLP)
        k_xgather<<<(E * 4 + 255) / 256, 256, 0, stream>>>(srcs, xbuf, xg, E);
        // fused aggregation + GEMM — streaming phase 1, degree-matched blocks
        k_zgemm<<<(N + 3) / 4, 256, 0, stream>>>(
            Hbuf, xg, offsets, counts, nodeperm, Bfrag, out, N);
        // lin2 + self-connection epilogue (in place on out)
        k_node_out<<<(N + 3) / 4, 256, 0, stream>>>(sbuf, w2n_ws, out, N);
    } else {
        hipMemsetAsync(d_out, 0, (size_t)out_size * sizeof(float), stream);
        k_edge_atomic<<<(E + EBS - 1) / EBS, EBS, 0, stream>>>(
            edge_features, fc_w1, fc_b1, fc_w2, fc_b2, edge_src, edge_dst, xbuf, out, E);
        k_node_out<<<(N + 3) / 4, 256, 0, stream>>>(sbuf, w2n_ws, out, N);
    }
}

// Round 17
// 272.896 us; speedup vs baseline: 1.0852x; 1.0852x over previous
//
#include <hip/hip_runtime.h>
#include <math.h>

// Problem dims (fixed by reference)
#define CC 4
#define FE 32
#define HH 64
#define EBS 256
#define KEXT 544          // 512 + 32 (8 xbar cols + 24 zero pad), 17 K-steps of 32
#define ASTR 69           // uint4 per A-tile LDS row

typedef __attribute__((ext_vector_type(8))) short bf16x8;
typedef __attribute__((ext_vector_type(4))) float f32x4;

// bf16 round-to-nearest-even pack
__device__ inline unsigned short f2bf(float f) {
    unsigned u = __float_as_uint(f);
    u += 0x7fffu + ((u >> 16) & 1u);
    return (unsigned short)(u >> 16);
}
__device__ inline float bf2f(unsigned short b) {
    return __uint_as_float(((unsigned)b) << 16);
}

// ---------------------------------------------------------------------------
// Node prep (one wave per node, shuffle-based, low-VGPR)
// ---------------------------------------------------------------------------
__global__ __launch_bounds__(256) void k_nodeprep(
    const float* __restrict__ node_input, const float* __restrict__ node_attr,
    const float* __restrict__ W_lin1, const float* __restrict__ W_sc,
    const float* __restrict__ W_lin2,
    float* __restrict__ xbuf, float* __restrict__ sbuf,
    float* __restrict__ w2n_ws, int N)
{
    const float c_s = 0.3826834323650898f;
    const float c_x_scaled = 0.9238795325112867f * 0.35355339059327373f; // c_x/sqrt(8)
    int node = blockIdx.x * 4 + (threadIdx.x >> 6);
    int lane = threadIdx.x & 63;
    if (node >= N) return;

    float attr_own = (lane < 16) ? node_attr[(size_t)node * 16 + lane] : 0.f;
    float ni_own   = (lane < 32) ? node_input[(size_t)node * 32 + lane] : 0.f;

    int iw = lane >> 3, jw = lane & 7;
    float wb1 = 0.f, wbs = 0.f, w2n = 0.f;
    #pragma unroll
    for (int a = 0; a < 16; ++a) {
        float fa = __shfl(attr_own, a);
        int idx = (iw * 16 + a) * 8 + jw;
        wb1 += fa * W_lin1[idx];
        wbs += fa * W_sc[idx];
        w2n += fa * W_lin2[idx];
    }
    w2n_ws[(size_t)node * 64 + lane] = c_x_scaled * w2n;

    int c_ = (lane >> 3) & 3, jo = lane & 7;
    float xo = 0.f, so = 0.f;
    #pragma unroll
    for (int i = 0; i < 8; ++i) {
        float niv = __shfl(ni_own, c_ * 8 + i);
        xo += niv * __shfl(wb1, i * 8 + jo);
        so += niv * __shfl(wbs, i * 8 + jo);
    }
    if (lane < 32) {
        xbuf[(size_t)node * 32 + lane] = xo;
        sbuf[(size_t)node * 32 + lane] = c_s * so;
    }
}

// ---------------------------------------------------------------------------
// CSR build over edge_dst
// ---------------------------------------------------------------------------
__global__ __launch_bounds__(256) void k_hist(
    const int* __restrict__ edge_dst, int* __restrict__ counts, int E)
{
    int e = blockIdx.x * 256 + threadIdx.x;
    if (e < E) atomicAdd(&counts[edge_dst[e]], 1);
}

// Parallel scan stage A: per-1024-tile exclusive scan + tile totals
__global__ __launch_bounds__(1024) void k_scanA(
    const int* __restrict__ counts, int* __restrict__ offsets,
    int* __restrict__ btot, int N)
{
    __shared__ int wsum[16];
    __shared__ int wpre[16];
    int tid = threadIdx.x, wid = tid >> 6, lane = tid & 63;
    int idx = blockIdx.x * 1024 + tid;
    int v = (idx < N) ? counts[idx] : 0;
    int x = v;
    #pragma unroll
    for (int s = 1; s < 64; s <<= 1) {
        int y = __shfl_up(x, s);
        if (lane >= s) x += y;
    }
    if (lane == 63) wsum[wid] = x;
    __syncthreads();
    if (wid == 0) {
        int wv = (lane < 16) ? wsum[lane] : 0;
        int wx = wv;
        #pragma unroll
        for (int s = 1; s < 16; s <<= 1) {
            int y = __shfl_up(wx, s);
            if (lane >= s) wx += y;
        }
        if (lane < 16) wpre[lane] = wx - wv;
    }
    __syncthreads();
    int excl = wpre[wid] + (x - v);
    if (idx < N) offsets[idx] = excl;
    if (tid == 1023) btot[blockIdx.x] = excl + v;
}

// stage B: single-block exclusive scan of tile totals (nb <= 1024)
__global__ __launch_bounds__(1024) void k_scanB(int* __restrict__ btot, int nb)
{
    __shared__ int wsum[16];
    __shared__ int wpre[16];
    int tid = threadIdx.x, wid = tid >> 6, lane = tid & 63;
    int v = (tid < nb) ? btot[tid] : 0;
    int x = v;
    #pragma unroll
    for (int s = 1; s < 64; s <<= 1) {
        int y = __shfl_up(x, s);
        if (lane >= s) x += y;
    }
    if (lane == 63) wsum[wid] = x;
    __syncthreads();
    if (wid == 0) {
        int wv = (lane < 16) ? wsum[lane] : 0;
        int wx = wv;
        #pragma unroll
        for (int s = 1; s < 16; s <<= 1) {
            int y = __shfl_up(wx, s);
            if (lane >= s) wx += y;
        }
        if (lane < 16) wpre[lane] = wx - wv;
    }
    __syncthreads();
    if (tid < nb) btot[tid] = wpre[wid] + (x - v);
}

// stage C: add tile offsets, write cursor
__global__ __launch_bounds__(256) void k_scanC(
    int* __restrict__ offsets, const int* __restrict__ btot,
    int* __restrict__ cursor, int N)
{
    int i = blockIdx.x * 256 + threadIdx.x;
    if (i < N) {
        int o = offsets[i] + btot[i >> 10];
        offsets[i] = o;
        cursor[i] = o;
    }
}

// fill permutation: esrc[pos] = {edge id, src}
__global__ __launch_bounds__(256) void k_fill(
    const int* __restrict__ edge_dst, const int* __restrict__ edge_src,
    int* __restrict__ cursor, int2* __restrict__ esrc, int E)
{
    int e = blockIdx.x * 256 + threadIdx.x;
    if (e < E) {
        int pos = atomicAdd(&cursor[edge_dst[e]], 1);
        int2 v; v.x = e; v.y = edge_src[e];
        esrc[pos] = v;
    }
}

// ---------------------------------------------------------------------------
// Pack W2 (+ b2 as K-rows 512..519, zeros 520..543) into MFMA B-frag order.
// ---------------------------------------------------------------------------
__global__ __launch_bounds__(256) void k_prep_bfrag(
    const float* __restrict__ fc_w2, const float* __restrict__ fc_b2,
    unsigned short* __restrict__ Bfrag)
{
    int t = blockIdx.x * 256 + threadIdx.x;
    if (t >= KEXT * 64) return;
    int kappa = t >> 6, nu = t & 63;
    int d = nu >> 3, o = nu & 7;
    float val;
    if (kappa < 512)      val = fc_w2[(size_t)(kappa >> 3) * 512 + d * 64 + (kappa & 7) * 8 + o];
    else if (kappa < 520) val = fc_b2[d * 64 + (kappa & 7) * 8 + o];
    else                  val = 0.f;
    int kk = kappa >> 5;
    int lane = ((kappa >> 3) & 3) * 16 + (nu & 15);
    int ct = nu >> 4;
    int j = kappa & 7;
    Bfrag[(size_t)((kk * 4 + ct) * 64 + lane) * 8 + j] = f2bf(val);
}

// ---------------------------------------------------------------------------
// Pack W1 [32,64] into MFMA B-frag order (one K-step).
// ---------------------------------------------------------------------------
__global__ __launch_bounds__(256) void k_prep_bfrag1(
    const float* __restrict__ fc_w1, unsigned short* __restrict__ Bfrag1)
{
    int t = blockIdx.x * 256 + threadIdx.x;
    if (t >= 4 * 64 * 8) return;
    int j = t & 7, l = (t >> 3) & 63, ct = t >> 9;
    int k = (l >> 4) * 8 + j;
    int n = ct * 16 + (l & 15);
    Bfrag1[t] = f2bf(fc_w1[(size_t)k * HH + n]);
}

// ---------------------------------------------------------------------------
// H build via MFMA (original edge order, linear writes, no LDS)
// ---------------------------------------------------------------------------
__global__ __launch_bounds__(256) void k_hsilu(
    const float* __restrict__ edge_features,
    const unsigned short* __restrict__ Bfrag1, const float* __restrict__ fc_b1,
    unsigned short* __restrict__ H, int E)
{
    int wid = threadIdx.x >> 6, lane = threadIdx.x & 63;
    int e0 = (blockIdx.x * 4 + wid) * 16;
    if (e0 >= E) return;

    bf16x8 b[4];
    #pragma unroll
    for (int ct = 0; ct < 4; ++ct) {
        uint4 bv = reinterpret_cast<const uint4*>(Bfrag1)[ct * 64 + lane];
        b[ct] = *reinterpret_cast<bf16x8*>(&bv);
    }
    float bias[4];
    #pragma unroll
    for (int ct = 0; ct < 4; ++ct) bias[ct] = fc_b1[ct * 16 + (lane & 15)];

    int row = e0 + (lane & 15);
    if (row >= E) row = E - 1;
    const float4* ap = reinterpret_cast<const float4*>(
        edge_features + (size_t)row * FE + (lane >> 4) * 8);
    float4 a0 = ap[0], a1 = ap[1];
    unsigned au[4];
    au[0] = (unsigned)f2bf(a0.x) | ((unsigned)f2bf(a0.y) << 16);
    au[1] = (unsigned)f2bf(a0.z) | ((unsigned)f2bf(a0.w) << 16);
    au[2] = (unsigned)f2bf(a1.x) | ((unsigned)f2bf(a1.y) << 16);
    au[3] = (unsigned)f2bf(a1.z) | ((unsigned)f2bf(a1.w) << 16);
    bf16x8 a = *reinterpret_cast<bf16x8*>(au);

    f32x4 acc[4];
    #pragma unroll
    for (int ct = 0; ct < 4; ++ct) {
        acc[ct] = (f32x4){0.f, 0.f, 0.f, 0.f};
        acc[ct] = __builtin_amdgcn_mfma_f32_16x16x32_bf16(a, b[ct], acc[ct], 0, 0, 0);
    }

    #pragma unroll
    for (int ct = 0; ct < 4; ++ct) {
        #pragma unroll
        for (int v = 0; v < 4; ++v) {
            int r = e0 + (lane >> 4) * 4 + v;
            if (r < E) {
                float x = acc[ct][v] + bias[ct];
                float s = x / (1.f + __expf(-x));
                H[(size_t)r * HH + ct * 16 + (lane & 15)] = f2bf(s);
            }
        }
    }
}

// ---------------------------------------------------------------------------
// FUSED zbuild + GEMM (round-10 proven form: 144 us, VGPR 48, occ 50%).
// Block = 4 waves = 4 nodes = one 16-row MFMA tile.
// Phase 1: lane k owns h[e,k]; per edge: 1 H row load (random, L3-hit) +
//          8 broadcast x float4 (xbuf is L2-resident) via esrc preload+shfl.
// Phase 2: pack A-tile (z rows + xbar + zero pad) into LDS.
// Phase 3: 17 MFMA per wave (wave = ct column tile). Raw agg -> out.
// ---------------------------------------------------------------------------
__global__ __launch_bounds__(256) void k_zgemm(
    const unsigned short* __restrict__ H, const int2* __restrict__ esrc,
    const int* __restrict__ offsets, const int* __restrict__ counts,
    const float* __restrict__ xin, const unsigned short* __restrict__ Bfrag,
    float* __restrict__ out, int N)
{
    __shared__ uint4 alds[16 * ASTR];   // 17664 B
    int wid = threadIdx.x >> 6, lane = threadIdx.x & 63;
    int node = blockIdx.x * 4 + wid;
    bool valid = (node < N);

    // ---- Phase 1: edge accumulation (lane k owns h[e,k]) ----
    float z[CC][8];
    #pragma unroll
    for (int c = 0; c < CC; ++c)
        #pragma unroll
        for (int i = 0; i < 8; ++i) z[c][i] = 0.f;
    float xsown = 0.f;

    int off = 0, cnt = 0;
    if (valid) { off = offsets[node]; cnt = counts[node]; }
    for (int base = 0; base < cnt; base += 64) {
        int m = (cnt - base < 64) ? (cnt - base) : 64;
        int2 ej = (lane < m) ? esrc[off + base + lane] : make_int2(0, 0);
        #pragma unroll 2
        for (int j = 0; j < m; ++j) {
            int e   = __shfl(ej.x, j);
            int src = __shfl(ej.y, j);
            float hk = bf2f(H[(size_t)e * HH + lane]);
            const float4* xp = reinterpret_cast<const float4*>(xin + (size_t)src * 32);
            float xs[32];
            #pragma unroll
            for (int q = 0; q < 8; ++q) {
                float4 v = xp[q];
                xs[q * 4 + 0] = v.x; xs[q * 4 + 1] = v.y;
                xs[q * 4 + 2] = v.z; xs[q * 4 + 3] = v.w;
            }
            #pragma unroll
            for (int c = 0; c < CC; ++c)
                #pragma unroll
                for (int i = 0; i < 8; ++i)
                    z[c][i] += hk * xs[c * 8 + i];
            xsown += xin[(size_t)src * 32 + (lane & 31)];
        }
    }

    // ---- Phase 2: pack this node's 4 rows into the LDS A-tile ----
    #pragma unroll
    for (int c = 0; c < CC; ++c) {
        uint4 pk;
        pk.x = (unsigned)f2bf(z[c][0]) | ((unsigned)f2bf(z[c][1]) << 16);
        pk.y = (unsigned)f2bf(z[c][2]) | ((unsigned)f2bf(z[c][3]) << 16);
        pk.z = (unsigned)f2bf(z[c][4]) | ((unsigned)f2bf(z[c][5]) << 16);
        pk.w = (unsigned)f2bf(z[c][6]) | ((unsigned)f2bf(z[c][7]) << 16);
        alds[(wid * 4 + c) * ASTR + lane] = pk;
    }
    float xb[8];
    #pragma unroll
    for (int i = 0; i < 8; ++i) xb[i] = __shfl(xsown, (lane & 3) * 8 + i);
    int r4 = wid * 4;
    if (lane < 4) {
        uint4 pk;
        pk.x = (unsigned)f2bf(xb[0]) | ((unsigned)f2bf(xb[1]) << 16);
        pk.y = (unsigned)f2bf(xb[2]) | ((unsigned)f2bf(xb[3]) << 16);
        pk.z = (unsigned)f2bf(xb[4]) | ((unsigned)f2bf(xb[5]) << 16);
        pk.w = (unsigned)f2bf(xb[6]) | ((unsigned)f2bf(xb[7]) << 16);
        alds[(r4 + lane) * ASTR + 64] = pk;
    } else if (lane < 16) {
        int j = lane - 4;
        uint4 zz; zz.x = 0u; zz.y = 0u; zz.z = 0u; zz.w = 0u;
        alds[(r4 + (j & 3)) * ASTR + 65 + (j >> 2)] = zz;
    }

    // ---- B fragments for ct = wid ----
    bf16x8 bfr[17];
    #pragma unroll
    for (int kk = 0; kk < 16; ++kk) {
        uint4 bv = reinterpret_cast<const uint4*>(Bfrag)[(kk * 4 + wid) * 64 + lane];
        bfr[kk] = *reinterpret_cast<bf16x8*>(&bv);
    }
    {
        uint4 bv = reinterpret_cast<const uint4*>(Bfrag)[(64 + wid) * 64 + lane];
        bfr[16] = *reinterpret_cast<bf16x8*>(&bv);
    }

    __syncthreads();

    // ---- Phase 3: GEMM, wave = ct ----
    f32x4 acc = (f32x4){0.f, 0.f, 0.f, 0.f};
    #pragma unroll
    for (int kk = 0; kk < 16; ++kk) {
        uint4 av = alds[(lane & 15) * ASTR + kk * 4 + (lane >> 4)];
        bf16x8 a = *reinterpret_cast<bf16x8*>(&av);
        acc = __builtin_amdgcn_mfma_f32_16x16x32_bf16(a, bfr[kk], acc, 0, 0, 0);
    }
    {
        uint4 av = alds[(lane & 15) * ASTR + 64 + (lane >> 4)];
        bf16x8 a = *reinterpret_cast<bf16x8*>(&av);
        acc = __builtin_amdgcn_mfma_f32_16x16x32_bf16(a, bfr[16], acc, 0, 0, 0);
    }

    int rbase = blockIdx.x * 16;
    int M = N * 4;
    #pragma unroll
    for (int v = 0; v < 4; ++v) {
        int r = rbase + (lane >> 4) * 4 + v;
        if (r < M)
            out[(size_t)r * 64 + wid * 16 + (lane & 15)] = acc[v];
    }
}

// ---------------------------------------------------------------------------
// Kernel C: shuffle lin2 + self-connection epilogue (in place on out).
// ---------------------------------------------------------------------------
__global__ __launch_bounds__(256) void k_node_out(
    const float* __restrict__ sbuf, const float* __restrict__ w2n_ws,
    float* __restrict__ out, int N)
{
    int node = blockIdx.x * 4 + (threadIdx.x >> 6);
    int lane = threadIdx.x & 63;
    if (node >= N) return;
    int d = lane >> 3, p = lane & 7;

    float w2 = w2n_ws[(size_t)node * 64 + lane];
    float s_own = sbuf[(size_t)node * 32 + (lane & 31)];

    float w2sh[8];
    #pragma unroll
    for (int o = 0; o < 8; ++o) w2sh[o] = __shfl(w2, o * 8 + p);

    float* rowp = out + (size_t)node * 256;
    #pragma unroll
    for (int c = 0; c < CC; ++c) {
        float a_own = rowp[c * 64 + lane];
        float res = 0.f;
        #pragma unroll
        for (int o = 0; o < 8; ++o)
            res += __shfl(a_own, d * 8 + o) * w2sh[o];
        float sval = __shfl(s_own, c * 8 + p);
        rowp[c * 64 + lane] = sval + res;
    }
}

// ---------------------------------------------------------------------------
// Fallback edge kernel (global atomics) — only if ws too small.
// ---------------------------------------------------------------------------
__global__ __launch_bounds__(EBS) void k_edge_atomic(
    const float* __restrict__ edge_features,
    const float* __restrict__ fc_w1, const float* __restrict__ fc_b1,
    const float* __restrict__ fc_w2, const float* __restrict__ fc_b2,
    const int* __restrict__ edge_src, const int* __restrict__ edge_dst,
    const float* __restrict__ xin, float* __restrict__ agg, int E)
{
    __shared__ float hlds[HH * EBS];
    int e = blockIdx.x * EBS + threadIdx.x;
    if (e >= E) return;
    float h[HH];
    #pragma unroll
    for (int k = 0; k < HH; ++k) h[k] = fc_b1[k];
    const float4* efp = reinterpret_cast<const float4*>(edge_features + (size_t)e * FE);
    #pragma unroll
    for (int fq = 0; fq < FE / 4; ++fq) {
        float4 efv = efp[fq];
        float ev[4] = {efv.x, efv.y, efv.z, efv.w};
        #pragma unroll
        for (int fs = 0; fs < 4; ++fs) {
            float evv = ev[fs];
            const float4* w1p = reinterpret_cast<const float4*>(fc_w1 + (fq * 4 + fs) * HH);
            #pragma unroll
            for (int q = 0; q < HH / 4; ++q) {
                float4 w = w1p[q];
                h[q * 4 + 0] += evv * w.x;
                h[q * 4 + 1] += evv * w.y;
                h[q * 4 + 2] += evv * w.z;
                h[q * 4 + 3] += evv * w.w;
            }
        }
    }
    #pragma unroll
    for (int k = 0; k < HH; ++k) {
        float v = h[k];
        hlds[k * EBS + threadIdx.x] = v / (1.f + __expf(-v));
    }
    int src = edge_src[e], dst = edge_dst[e];
    float xs[32];
    const float4* xp = reinterpret_cast<const float4*>(xin + (size_t)src * 32);
    #pragma unroll
    for (int q = 0; q < 8; ++q) {
        float4 v = xp[q];
        xs[q * 4 + 0] = v.x; xs[q * 4 + 1] = v.y;
        xs[q * 4 + 2] = v.z; xs[q * 4 + 3] = v.w;
    }
    float* outp = agg + (size_t)dst * 256;
    #pragma unroll 1
    for (int d = 0; d < 8; ++d) {
        float t[64];
        const float4* b2p = reinterpret_cast<const float4*>(fc_b2 + d * 64);
        #pragma unroll
        for (int q = 0; q < 16; ++q) {
            float4 v = b2p[q];
            t[q * 4 + 0] = v.x; t[q * 4 + 1] = v.y;
            t[q * 4 + 2] = v.z; t[q * 4 + 3] = v.w;
        }
        for (int k = 0; k < HH; ++k) {
            float hv = hlds[k * EBS + threadIdx.x];
            const float4* wp = reinterpret_cast<const float4*>(fc_w2 + (size_t)k * 512 + d * 64);
            #pragma unroll
            for (int q = 0; q < 16; ++q) {
                float4 w = wp[q];
                t[q * 4 + 0] += hv * w.x;
                t[q * 4 + 1] += hv * w.y;
                t[q * 4 + 2] += hv * w.z;
                t[q * 4 + 3] += hv * w.w;
            }
        }
        #pragma unroll
        for (int c = 0; c < CC; ++c) {
            #pragma unroll
            for (int o = 0; o < 8; ++o) {
                float acc = 0.f;
                #pragma unroll
                for (int i = 0; i < 8; ++i) acc += xs[c * 8 + i] * t[i * 8 + o];
                atomicAdd(outp + c * 64 + d * 8 + o, acc);
            }
        }
    }
}

// ---------------------------------------------------------------------------
extern "C" void kernel_launch(void* const* d_in, const int* in_sizes, int n_in,
                              void* d_out, int out_size, void* d_ws, size_t ws_size,
                              hipStream_t stream)
{
    const float* node_input    = (const float*)d_in[0];
    const float* node_attr     = (const float*)d_in[1];
    const float* edge_features = (const float*)d_in[2];
    const float* W_sc          = (const float*)d_in[3];
    const float* W_lin1        = (const float*)d_in[4];
    const float* W_lin2        = (const float*)d_in[5];
    const float* fc_w1         = (const float*)d_in[6];
    const float* fc_b1         = (const float*)d_in[7];
    const float* fc_w2         = (const float*)d_in[8];
    const float* fc_b2         = (const float*)d_in[9];
    const int*   edge_src      = (const int*)d_in[10];
    const int*   edge_dst      = (const int*)d_in[11];

    const int N = in_sizes[1] / 16;
    const int E = in_sizes[10];
    const int nb = (N + 1023) / 1024;

    char* ws = (char*)d_ws;
    size_t off = 0;
    auto take = [&](size_t bytes) { char* p = ws + off; off += (bytes + 15) & ~(size_t)15; return p; };
    float* xbuf            = (float*)take((size_t)N * 32 * sizeof(float));
    float* sbuf            = (float*)take((size_t)N * 32 * sizeof(float));
    float* w2n_ws          = (float*)take((size_t)N * 64 * sizeof(float));
    int*   counts          = (int*)take((size_t)N * sizeof(int));
    int*   offsets         = (int*)take((size_t)N * sizeof(int));
    int*   cursor          = (int*)take((size_t)N * sizeof(int));
    int*   btot            = (int*)take((size_t)1024 * sizeof(int));
    int2*  esrc            = (int2*)take((size_t)E * sizeof(int2));
    unsigned short* Bfrag  = (unsigned short*)take((size_t)17 * 4 * 64 * 8 * sizeof(unsigned short));
    unsigned short* Bfrag1 = (unsigned short*)take((size_t)4 * 64 * 8 * sizeof(unsigned short));
    unsigned short* Hbuf   = (unsigned short*)take((size_t)E * HH * sizeof(unsigned short));
    bool fast = (off <= ws_size);

    float* out = (float*)d_out;

    // node prep: x, c_s*s, w2n (one wave per node, shuffle-based)
    k_nodeprep<<<(N + 3) / 4, 256, 0, stream>>>(
        node_input, node_attr, W_lin1, W_sc, W_lin2, xbuf, sbuf, w2n_ws, N);

    if (fast) {
        // CSR over edge_dst ({e,src} gather), parallel scan
        hipMemsetAsync(counts, 0, (size_t)N * sizeof(int), stream);
        k_hist<<<(E + 255) / 256, 256, 0, stream>>>(edge_dst, counts, E);
        k_scanA<<<nb, 1024, 0, stream>>>(counts, offsets, btot, N);
        k_scanB<<<1, 1024, 0, stream>>>(btot, nb);
        k_scanC<<<(N + 255) / 256, 256, 0, stream>>>(offsets, btot, cursor, N);
        k_fill<<<(E + 255) / 256, 256, 0, stream>>>(edge_dst, edge_src, cursor, esrc, E);
        // weight packs
        k_prep_bfrag1<<<(4 * 64 * 8 + 255) / 256, 256, 0, stream>>>(fc_w1, Bfrag1);
        k_prep_bfrag<<<(KEXT * 64 + 255) / 256, 256, 0, stream>>>(fc_w2, fc_b2, Bfrag);
        // radial layer-1 via MFMA (linear, coalesced H writes)
        k_hsilu<<<(E + 63) / 64, 256, 0, stream>>>(edge_features, Bfrag1, fc_b1, Hbuf, E);
        // fused aggregation + GEMM (raw agg -> out)
        k_zgemm<<<(N + 3) / 4, 256, 0, stream>>>(
            Hbuf, esrc, offsets, counts, xbuf, Bfrag, out, N);
        // lin2 + self-connection epilogue (in place on out)
        k_node_out<<<(N + 3) / 4, 256, 0, stream>>>(sbuf, w2n_ws, out, N);
    } else {
        hipMemsetAsync(d_out, 0, (size_t)out_size * sizeof(float), stream);
        k_edge_atomic<<<(E + EBS - 1) / EBS, EBS, 0, stream>>>(
            edge_features, fc_w1, fc_b1, fc_w2, fc_b2, edge_src, edge_dst, xbuf, out, E);
        k_node_out<<<(N + 3) / 4, 256, 0, stream>>>(sbuf, w2n_ws, out, N);
    }
}